// Round 4
// baseline (196.446 us; speedup 1.0000x reference)
//
#include <hip/hip_runtime.h>

#define BATCH 8
#define S_LEN 2048
#define DDIM 512
#define UDIM 512
#define WIN_L 128
#define WIN_R 128
#define QT 16        // q-rows per block
#define NSTRIP 272   // strip keys = QT + WIN_L + WIN_R
#define NTILE 17     // 16-key S-tiles per strip
#define PP 296       // P pitch (f16), covers 288 (9*32) PV cols + pad
#define QP 520       // Q LDS pitch (f16): 512 + 8, 16B-aligned rows, 2-way max aliasing

typedef _Float16 f16;
typedef __attribute__((ext_vector_type(8))) _Float16 f16x8;
typedef __attribute__((ext_vector_type(4))) _Float16 f16x4;
typedef __attribute__((ext_vector_type(4))) float f32x4;

__device__ __forceinline__ void gload_lds16(const void* g, void* l) {
  __builtin_amdgcn_global_load_lds((const __attribute__((address_space(1))) void*)g,
                                   (__attribute__((address_space(3))) void*)l, 16, 0, 0);
}

// ---------------- cast x (fp32) -> f16 ----------------
__global__ void cast_f32_f16(const float* __restrict__ in, f16* __restrict__ out, int n) {
  int i = (blockIdx.x * blockDim.x + threadIdx.x) * 4;
  if (i < n) {
    float4 v = *(const float4*)(in + i);
    f16x4 o;
    o[0] = (f16)v.x; o[1] = (f16)v.y; o[2] = (f16)v.z; o[3] = (f16)v.w;
    *(f16x4*)(out + i) = o;
  }
}

// ---------------- transpose W [D][U] fp32 -> WT [U][D] f16 (3 matrices) ----------------
__global__ void transpose_w(const float* __restrict__ Wq, const float* __restrict__ Wk,
                            const float* __restrict__ Wv, f16* __restrict__ WT) {
  const float* W = blockIdx.z == 0 ? Wq : (blockIdx.z == 1 ? Wk : Wv);
  f16* WTz = WT + (size_t)blockIdx.z * DDIM * UDIM;
  __shared__ float t[32][33];
  int tx = threadIdx.x & 31, ty = threadIdx.x >> 5;  // 32 x 8
  int n0 = blockIdx.x * 32, k0 = blockIdx.y * 32;
  for (int i = 0; i < 4; i++) {
    int r = ty * 4 + i;
    t[r][tx] = W[(size_t)(k0 + r) * UDIM + n0 + tx];
  }
  __syncthreads();
  for (int i = 0; i < 4; i++) {
    int r = ty * 4 + i;
    WTz[(size_t)(n0 + r) * DDIM + k0 + tx] = (f16)t[tx][r];
  }
}

// ---------------- QKV GEMM (unchanged, m97 structure, BK=64) ----------------
__global__ __launch_bounds__(256, 2) void gemm_qkv(
    const f16* __restrict__ X, const f16* __restrict__ WT,
    const float* __restrict__ bq, const float* __restrict__ bk, const float* __restrict__ bv,
    f16* __restrict__ QKV, f16* __restrict__ VT) {
  int z = blockIdx.z;
  const f16* WTz = WT + (size_t)z * DDIM * UDIM;   // [U][D] layout
  const float* bias = z == 0 ? bq : (z == 1 ? bk : bv);
  f16* out = QKV + (size_t)z * (BATCH * S_LEN) * UDIM;

  __shared__ f16 Al[2][128 * 32];
  __shared__ f16 Bl[2][128 * 32];

  int tid = threadIdx.x, wv = tid >> 6, ln = tid & 63;
  int m0 = blockIdx.x * 128, n0 = blockIdx.y * 128;
  int wm = (wv >> 1) * 64, wn = (wv & 1) * 64;
  int lm = ln & 15, lq = ln >> 4;
  int srow = ln >> 2, scol = (ln & 3) * 8;

  f32x4 acc[4][4];
  for (int mt = 0; mt < 4; mt++)
    for (int nt = 0; nt < 4; nt++)
      for (int r = 0; r < 4; r++) acc[mt][nt][r] = 0.f;

  for (int k0 = 0; k0 < DDIM; k0 += 64) {
    for (int half = 0; half < 2; half++) {
      int r0 = half * 64 + wv * 16;  // wave-uniform
      for (int c = 0; c < 2; c++) {
        gload_lds16(X + (size_t)(m0 + r0 + srow) * DDIM + k0 + c * 32 + scol, &Al[c][r0 * 32]);
        gload_lds16(WTz + (size_t)(n0 + r0 + srow) * DDIM + k0 + c * 32 + scol, &Bl[c][r0 * 32]);
      }
    }
    __syncthreads();
#pragma unroll
    for (int c = 0; c < 2; c++) {
      f16x8 af[4], bfr[4];
      for (int mt = 0; mt < 4; mt++) af[mt] = *(const f16x8*)&Al[c][(wm + mt * 16 + lm) * 32 + lq * 8];
      for (int nt = 0; nt < 4; nt++) bfr[nt] = *(const f16x8*)&Bl[c][(wn + nt * 16 + lm) * 32 + lq * 8];
      for (int mt = 0; mt < 4; mt++)
        for (int nt = 0; nt < 4; nt++)
          acc[mt][nt] = __builtin_amdgcn_mfma_f32_16x16x32_f16(af[mt], bfr[nt], acc[mt][nt], 0, 0, 0);
    }
    __syncthreads();
  }

  if (z == 2) {
    for (int mt = 0; mt < 4; mt++)
      for (int nt = 0; nt < 4; nt++) {
        int col = n0 + wn + nt * 16 + lm;          // u
        float bv_ = bias[col];
        int row0 = m0 + wm + mt * 16 + lq * 4;     // global s index (r=0)
        int bb = row0 >> 11, ss = row0 & 2047;
        f16x4 o;
        for (int r = 0; r < 4; r++) o[r] = (f16)(acc[mt][nt][r] + bv_);
        *(f16x4*)&VT[((size_t)bb * UDIM + col) * S_LEN + ss] = o;
      }
  } else {
    for (int mt = 0; mt < 4; mt++)
      for (int nt = 0; nt < 4; nt++) {
        int col = n0 + wn + nt * 16 + lm;
        float bv_ = bias[col];
        for (int r = 0; r < 4; r++) {
          int row = m0 + wm + mt * 16 + lq * 4 + r;
          out[(size_t)row * UDIM + col] = (f16)(acc[mt][nt][r] + bv_);
        }
      }
  }
}

// ---------------- single-pass sliding-window attention, v4 ----------------
// 16-row q-tile per block -> grid (8,128) = 1024 blocks = 4 blocks/CU = 16 waves/CU.
// Q staged in LDS (A-frags via ds_read), freeing VGPRs for deep K/V L2-load pipelining.
// Waves split the 17 S-tiles round-robin (no K duplication in block) and split PV by u.
__global__ __launch_bounds__(256, 4) void attn(
    const f16* __restrict__ Q, const f16* __restrict__ K, const f16* __restrict__ VT,
    float* __restrict__ out) {
  __shared__ f16 Ql[QT * QP];          // 16.6 KB
  __shared__ f16 Pb[QT * PP];          // 9.5 KB
  __shared__ float wmax[4][QT], wsum[4][QT];

  int tid = threadIdx.x, wv = tid >> 6, ln = tid & 63;
  int lm = ln & 15, lq = ln >> 4;
  int b = blockIdx.x, q0 = blockIdx.y * QT;
  const size_t base = (size_t)b * S_LEN;
  const int strip0 = q0 - WIN_L;       // keys [strip0, strip0 + 272)

  // zero P tail cols [272, 288) (PV reads 9*32 = 288 cols)
  { int zr = tid >> 4, zc = 272 + (tid & 15); Pb[zr * PP + zc] = (f16)0.f; }

  // stage Q rows into LDS: one global_load_lds per row (64 lanes x 16B = full row)
  for (int r = 0; r < 4; r++) {
    int row = wv * 4 + r;
    gload_lds16(Q + (base + q0 + row) * (size_t)DDIM + ln * 8, &Ql[row * QP]);
  }
  __syncthreads();  // barrier 0: Q + P-tail ready

  // ---- S phase: wave wv handles tiles t = wv, wv+4, ... (<17) ----
  const float scale = 0.044194173824159216f;  // 1/sqrt(512)
  f32x4 sacc[5];
  float mx[4] = {-1e30f, -1e30f, -1e30f, -1e30f};
#pragma unroll
  for (int i = 0; i < 5; i++) {
    int t = wv + i * 4;
    if (t >= NTILE) break;  // wave-uniform
    int key = strip0 + t * 16 + lm;
    int t0 = strip0 + t * 16;
    bool live = (t0 + 15 >= 0) && (t0 < S_LEN);  // wave-uniform
    int kc = key < 0 ? 0 : (key > S_LEN - 1 ? S_LEN - 1 : key);
    const f16* kp = K + (base + kc) * (size_t)DDIM + lq * 8;
    f32x4 s0, s1;
    for (int r = 0; r < 4; r++) { s0[r] = 0.f; s1[r] = 0.f; }
    if (live) {
#pragma unroll
      for (int kk = 0; kk < 16; kk += 2) {
        f16x8 qa = *(const f16x8*)&Ql[lm * QP + kk * 32 + lq * 8];
        f16x8 qb = *(const f16x8*)&Ql[lm * QP + (kk + 1) * 32 + lq * 8];
        f16x8 k0 = *(const f16x8*)(kp + kk * 32);
        f16x8 k1 = *(const f16x8*)(kp + (kk + 1) * 32);
        s0 = __builtin_amdgcn_mfma_f32_16x16x32_f16(qa, k0, s0, 0, 0, 0);
        s1 = __builtin_amdgcn_mfma_f32_16x16x32_f16(qb, k1, s1, 0, 0, 0);
      }
    }
#pragma unroll
    for (int r = 0; r < 4; r++) {
      int qi = q0 + lq * 4 + r;
      float s = (s0[r] + s1[r]) * scale;
      bool ok = (key >= 0) && (key < S_LEN) && (key >= qi - WIN_L) && (key <= qi + WIN_R);
      s = ok ? s : -1e30f;
      sacc[i][r] = s;
      mx[r] = fmaxf(mx[r], s);
    }
  }
#pragma unroll
  for (int r = 0; r < 4; r++) {
    mx[r] = fmaxf(mx[r], __shfl_xor(mx[r], 1));
    mx[r] = fmaxf(mx[r], __shfl_xor(mx[r], 2));
    mx[r] = fmaxf(mx[r], __shfl_xor(mx[r], 4));
    mx[r] = fmaxf(mx[r], __shfl_xor(mx[r], 8));
  }
  if (lm == 0) {
#pragma unroll
    for (int r = 0; r < 4; r++) wmax[wv][lq * 4 + r] = mx[r];
  }
  __syncthreads();  // barrier 1: row maxima

  // ---- exp + P park + row sums ----
  float mrow[4], sum[4] = {0.f, 0.f, 0.f, 0.f};
#pragma unroll
  for (int r = 0; r < 4; r++) {
    int row = lq * 4 + r;
    mrow[r] = fmaxf(fmaxf(wmax[0][row], wmax[1][row]), fmaxf(wmax[2][row], wmax[3][row]));
  }
#pragma unroll
  for (int i = 0; i < 5; i++) {
    int t = wv + i * 4;
    if (t >= NTILE) break;
#pragma unroll
    for (int r = 0; r < 4; r++) {
      float p = __expf(sacc[i][r] - mrow[r]);
      sum[r] += p;
      Pb[(lq * 4 + r) * PP + t * 16 + lm] = (f16)p;
    }
  }
#pragma unroll
  for (int r = 0; r < 4; r++) {
    sum[r] += __shfl_xor(sum[r], 1);
    sum[r] += __shfl_xor(sum[r], 2);
    sum[r] += __shfl_xor(sum[r], 4);
    sum[r] += __shfl_xor(sum[r], 8);
  }
  if (lm == 0) {
#pragma unroll
    for (int r = 0; r < 4; r++) wsum[wv][lq * 4 + r] = sum[r];
  }
  __syncthreads();  // barrier 2: P + sums

  // ---- PV: O[16 x 128-u-slice] = P[16x288] * V[288 x u]; wave owns u in [wv*128, +128) ----
  f32x4 oacc[8];
#pragma unroll
  for (int nt = 0; nt < 8; nt++)
    for (int r = 0; r < 4; r++) oacc[nt][r] = 0.f;

  const f16* vb = VT + ((size_t)b * UDIM + wv * 128 + lm) * S_LEN;
#pragma unroll
  for (int kst = 0; kst < 9; kst++) {
    f16x8 pf = *(const f16x8*)&Pb[lm * PP + kst * 32 + lq * 8];
    int key = strip0 + kst * 32 + lq * 8;
    int kc = key < 0 ? 0 : (key > S_LEN - 8 ? S_LEN - 8 : key);  // aligned clamp; P=0 where masked
#pragma unroll
    for (int nt = 0; nt < 8; nt++) {
      f16x8 vv = *(const f16x8*)(vb + (size_t)(nt * 16) * S_LEN + kc);
      oacc[nt] = __builtin_amdgcn_mfma_f32_16x16x32_f16(pf, vv, oacc[nt], 0, 0, 0);
    }
  }

  // ---- epilogue: O /= l, fp32 store ----
  float linv[4];
#pragma unroll
  for (int r = 0; r < 4; r++) {
    int row = lq * 4 + r;
    linv[r] = 1.0f / (wsum[0][row] + wsum[1][row] + wsum[2][row] + wsum[3][row]);
  }
#pragma unroll
  for (int nt = 0; nt < 8; nt++)
    for (int r = 0; r < 4; r++) {
      int row = q0 + lq * 4 + r;
      int col = wv * 128 + nt * 16 + lm;
      out[(base + row) * (size_t)UDIM + col] = oacc[nt][r] * linv[r];
    }
}

extern "C" void kernel_launch(void* const* d_in, const int* in_sizes, int n_in,
                              void* d_out, int out_size, void* d_ws, size_t ws_size,
                              hipStream_t stream) {
  const float* x  = (const float*)d_in[0];
  const float* Wq = (const float*)d_in[1];
  const float* Wk = (const float*)d_in[2];
  const float* Wv = (const float*)d_in[3];
  const float* bq = (const float*)d_in[4];
  const float* bk = (const float*)d_in[5];
  const float* bv = (const float*)d_in[6];
  float* out = (float*)d_out;

  char* ws = (char*)d_ws;
  const size_t XB_BYTES  = (size_t)BATCH * S_LEN * DDIM * 2;       // 16.8 MB
  const size_t WT_BYTES  = (size_t)3 * DDIM * UDIM * 2;            // 1.5 MB
  const size_t QKV_BYTES = (size_t)3 * BATCH * S_LEN * UDIM * 2;   // 50.3 MB
  f16* xb  = (f16*)ws;
  f16* WT  = (f16*)(ws + XB_BYTES);
  f16* QKV = (f16*)(ws + XB_BYTES + WT_BYTES);
  f16* VT  = (f16*)(ws + XB_BYTES + WT_BYTES + QKV_BYTES);

  int n = BATCH * S_LEN * DDIM;
  cast_f32_f16<<<n / (256 * 4), 256, 0, stream>>>(x, xb, n);
  transpose_w<<<dim3(16, 16, 3), 256, 0, stream>>>(Wq, Wk, Wv, WT);
  gemm_qkv<<<dim3(128, 4, 3), 256, 0, stream>>>(xb, WT, bq, bk, bv, QKV, VT);
  // attn: blockIdx.x = batch so linear id % 8 == batch -> XCD-local K/V in L2
  attn<<<dim3(BATCH, S_LEN / QT), 256, 0, stream>>>(
      QKV, QKV + (size_t)BATCH * S_LEN * UDIM, VT, out);
}

// Round 5
// 155.039 us; speedup vs baseline: 1.2671x; 1.2671x over previous
//
#include <hip/hip_runtime.h>

#define BATCH 8
#define S_LEN 2048
#define DDIM 512
#define UDIM 512
#define WIN_L 128
#define WIN_R 128
#define KP 520   // K LDS pitch (f16): 512 + 8, rows 16B aligned
#define VP 40    // V LDS pitch (f16): 32 + 8
#define PP 296   // P LDS pitch (f16)

typedef _Float16 f16;
typedef __attribute__((ext_vector_type(8))) _Float16 f16x8;
typedef __attribute__((ext_vector_type(4))) _Float16 f16x4;
typedef __attribute__((ext_vector_type(4))) float f32x4;

__device__ __forceinline__ void gload_lds16(const void* g, void* l) {
  __builtin_amdgcn_global_load_lds((const __attribute__((address_space(1))) void*)g,
                                   (__attribute__((address_space(3))) void*)l, 16, 0, 0);
}

// ---------------- cast x (fp32) -> f16 ----------------
__global__ void cast_f32_f16(const float* __restrict__ in, f16* __restrict__ out, int n) {
  int i = (blockIdx.x * blockDim.x + threadIdx.x) * 4;
  if (i < n) {
    float4 v = *(const float4*)(in + i);
    f16x4 o;
    o[0] = (f16)v.x; o[1] = (f16)v.y; o[2] = (f16)v.z; o[3] = (f16)v.w;
    *(f16x4*)(out + i) = o;
  }
}

// ---------------- transpose W [D][U] fp32 -> WT [U][D] f16 (3 matrices) ----------------
__global__ void transpose_w(const float* __restrict__ Wq, const float* __restrict__ Wk,
                            const float* __restrict__ Wv, f16* __restrict__ WT) {
  const float* W = blockIdx.z == 0 ? Wq : (blockIdx.z == 1 ? Wk : Wv);
  f16* WTz = WT + (size_t)blockIdx.z * DDIM * UDIM;
  __shared__ float t[32][33];
  int tx = threadIdx.x & 31, ty = threadIdx.x >> 5;  // 32 x 8
  int n0 = blockIdx.x * 32, k0 = blockIdx.y * 32;
  for (int i = 0; i < 4; i++) {
    int r = ty * 4 + i;
    t[r][tx] = W[(size_t)(k0 + r) * UDIM + n0 + tx];
  }
  __syncthreads();
  for (int i = 0; i < 4; i++) {
    int r = ty * 4 + i;
    WTz[(size_t)(n0 + r) * DDIM + k0 + tx] = (f16)t[tx][r];
  }
}

// ---------------- QKV GEMM (m97 structure, BK=64) ----------------
__global__ __launch_bounds__(256, 2) void gemm_qkv(
    const f16* __restrict__ X, const f16* __restrict__ WT,
    const float* __restrict__ bq, const float* __restrict__ bk, const float* __restrict__ bv,
    f16* __restrict__ QKV, f16* __restrict__ VT) {
  int z = blockIdx.z;
  const f16* WTz = WT + (size_t)z * DDIM * UDIM;   // [U][D] layout
  const float* bias = z == 0 ? bq : (z == 1 ? bk : bv);
  f16* out = QKV + (size_t)z * (BATCH * S_LEN) * UDIM;

  __shared__ f16 Al[2][128 * 32];
  __shared__ f16 Bl[2][128 * 32];

  int tid = threadIdx.x, wv = tid >> 6, ln = tid & 63;
  int m0 = blockIdx.x * 128, n0 = blockIdx.y * 128;
  int wm = (wv >> 1) * 64, wn = (wv & 1) * 64;
  int lm = ln & 15, lq = ln >> 4;
  int srow = ln >> 2, scol = (ln & 3) * 8;

  f32x4 acc[4][4];
  for (int mt = 0; mt < 4; mt++)
    for (int nt = 0; nt < 4; nt++)
      for (int r = 0; r < 4; r++) acc[mt][nt][r] = 0.f;

  for (int k0 = 0; k0 < DDIM; k0 += 64) {
    for (int half = 0; half < 2; half++) {
      int r0 = half * 64 + wv * 16;  // wave-uniform
      for (int c = 0; c < 2; c++) {
        gload_lds16(X + (size_t)(m0 + r0 + srow) * DDIM + k0 + c * 32 + scol, &Al[c][r0 * 32]);
        gload_lds16(WTz + (size_t)(n0 + r0 + srow) * DDIM + k0 + c * 32 + scol, &Bl[c][r0 * 32]);
      }
    }
    __syncthreads();
#pragma unroll
    for (int c = 0; c < 2; c++) {
      f16x8 af[4], bfr[4];
      for (int mt = 0; mt < 4; mt++) af[mt] = *(const f16x8*)&Al[c][(wm + mt * 16 + lm) * 32 + lq * 8];
      for (int nt = 0; nt < 4; nt++) bfr[nt] = *(const f16x8*)&Bl[c][(wn + nt * 16 + lm) * 32 + lq * 8];
      for (int mt = 0; mt < 4; mt++)
        for (int nt = 0; nt < 4; nt++)
          acc[mt][nt] = __builtin_amdgcn_mfma_f32_16x16x32_f16(af[mt], bfr[nt], acc[mt][nt], 0, 0, 0);
    }
    __syncthreads();
  }

  if (z == 2) {
    for (int mt = 0; mt < 4; mt++)
      for (int nt = 0; nt < 4; nt++) {
        int col = n0 + wn + nt * 16 + lm;          // u
        float bv_ = bias[col];
        int row0 = m0 + wm + mt * 16 + lq * 4;     // global s index (r=0)
        int bb = row0 >> 11, ss = row0 & 2047;
        f16x4 o;
        for (int r = 0; r < 4; r++) o[r] = (f16)(acc[mt][nt][r] + bv_);
        *(f16x4*)&VT[((size_t)bb * UDIM + col) * S_LEN + ss] = o;
      }
  } else {
    for (int mt = 0; mt < 4; mt++)
      for (int nt = 0; nt < 4; nt++) {
        int col = n0 + wn + nt * 16 + lm;
        float bv_ = bias[col];
        for (int r = 0; r < 4; r++) {
          int row = m0 + wm + mt * 16 + lq * 4 + r;
          out[(size_t)row * UDIM + col] = (f16)(acc[mt][nt][r] + bv_);
        }
      }
  }
}

// ---------------- sliding-window attention, v5: m97-style LDS staging ----------------
// 32-row q-tile, grid (8,64) = 512 blocks, 2 blocks/CU. Both phases stage operands
// into LDS (K via async global_load_lds, V via VGPR copies) so load latency is
// covered by many outstanding requests instead of per-wave VGPR pipelining.
__global__ __launch_bounds__(256, 2) void attn(
    const f16* __restrict__ Q, const f16* __restrict__ K, const f16* __restrict__ VT,
    float* __restrict__ out) {
  __shared__ __align__(16) char ubuf[VP * 512 * 2];  // 40960 B: Kl (33.3KB) / Vl (40KB) union
  __shared__ f16 Pb[32 * PP];                        // 18.9 KB
  __shared__ float wmax[2][32], wsum[2][32];
  f16* Kl = (f16*)ubuf;
  f16* Vl = (f16*)ubuf;

  int tid = threadIdx.x, wv = tid >> 6, ln = tid & 63;
  int lm = ln & 15, lq = ln >> 4;
  int b = blockIdx.x, q0 = blockIdx.y * 32;
  int rh = wv >> 1, kh = wv & 1;        // wave quarter: q-rows rh*16.., keys kh*16..
  const size_t base = (size_t)b * S_LEN;
  const int strip0 = q0 - WIN_L;        // strip keys [strip0, strip0+288)

  // ---- Q fragments (A-operand), invariant ----
  f16x8 qf[16];
  {
    const f16* qrow = Q + (base + q0 + rh * 16 + lm) * (size_t)DDIM + lq * 8;
#pragma unroll
    for (int kk = 0; kk < 16; kk++) qf[kk] = *(const f16x8*)(qrow + kk * 32);
  }

  // ---- S phase: 9 staged key-steps ----
  f32x4 sacc[9];
#pragma unroll
  for (int s = 0; s < 9; s++)
    for (int r = 0; r < 4; r++) sacc[s][r] = 0.f;

#pragma unroll
  for (int s = 0; s < 9; s++) {
    int j0 = strip0 + s * 32;
    if (j0 + 31 >= 0 && j0 < S_LEN) {  // block-uniform liveness
      // stage 32 K rows (1KB each) via async global_load_lds; 8 rows per wave
#pragma unroll
      for (int i = 0; i < 8; i++) {
        int row = wv * 8 + i;
        int key = j0 + row;
        int kc = key < 0 ? 0 : (key > S_LEN - 1 ? S_LEN - 1 : key);
        gload_lds16(K + (base + kc) * (size_t)DDIM + ln * 8, &Kl[row * KP]);
      }
      __syncthreads();
      f32x4 s0, s1;
      for (int r = 0; r < 4; r++) { s0[r] = 0.f; s1[r] = 0.f; }
#pragma unroll
      for (int kk = 0; kk < 16; kk += 2) {
        f16x8 b0 = *(const f16x8*)&Kl[(kh * 16 + lm) * KP + kk * 32 + lq * 8];
        f16x8 b1 = *(const f16x8*)&Kl[(kh * 16 + lm) * KP + (kk + 1) * 32 + lq * 8];
        s0 = __builtin_amdgcn_mfma_f32_16x16x32_f16(qf[kk], b0, s0, 0, 0, 0);
        s1 = __builtin_amdgcn_mfma_f32_16x16x32_f16(qf[kk + 1], b1, s1, 0, 0, 0);
      }
      for (int r = 0; r < 4; r++) sacc[s][r] = s0[r] + s1[r];
      __syncthreads();
    }
  }

  // ---- mask + row max ----
  const float scale = 0.044194173824159216f;  // 1/sqrt(512)
  float mx[4] = {-1e30f, -1e30f, -1e30f, -1e30f};
#pragma unroll
  for (int s = 0; s < 9; s++) {
    int kj = strip0 + s * 32 + kh * 16 + lm;
#pragma unroll
    for (int r = 0; r < 4; r++) {
      int qi = q0 + rh * 16 + lq * 4 + r;
      float v = sacc[s][r] * scale;
      bool ok = (kj >= 0) && (kj < S_LEN) && (kj >= qi - WIN_L) && (kj <= qi + WIN_R);
      v = ok ? v : -1e30f;
      sacc[s][r] = v;
      mx[r] = fmaxf(mx[r], v);
    }
  }
#pragma unroll
  for (int r = 0; r < 4; r++) {
    mx[r] = fmaxf(mx[r], __shfl_xor(mx[r], 1));
    mx[r] = fmaxf(mx[r], __shfl_xor(mx[r], 2));
    mx[r] = fmaxf(mx[r], __shfl_xor(mx[r], 4));
    mx[r] = fmaxf(mx[r], __shfl_xor(mx[r], 8));
  }
  if (lm == 0) {
#pragma unroll
    for (int r = 0; r < 4; r++) wmax[kh][rh * 16 + lq * 4 + r] = mx[r];
  }
  __syncthreads();

  // ---- exp + P park + row sums ----
  float mrow[4], sum[4] = {0.f, 0.f, 0.f, 0.f};
#pragma unroll
  for (int r = 0; r < 4; r++) {
    int row = rh * 16 + lq * 4 + r;
    mrow[r] = fmaxf(wmax[0][row], wmax[1][row]);
  }
#pragma unroll
  for (int s = 0; s < 9; s++) {
#pragma unroll
    for (int r = 0; r < 4; r++) {
      float p = __expf(sacc[s][r] - mrow[r]);
      sum[r] += p;
      Pb[(rh * 16 + lq * 4 + r) * PP + s * 32 + kh * 16 + lm] = (f16)p;
    }
  }
#pragma unroll
  for (int r = 0; r < 4; r++) {
    sum[r] += __shfl_xor(sum[r], 1);
    sum[r] += __shfl_xor(sum[r], 2);
    sum[r] += __shfl_xor(sum[r], 4);
    sum[r] += __shfl_xor(sum[r], 8);
  }
  if (lm == 0) {
#pragma unroll
    for (int r = 0; r < 4; r++) wsum[kh][rh * 16 + lq * 4 + r] = sum[r];
  }
  __syncthreads();  // Pb + sums visible; Kl dead -> Vl may reuse ubuf

  // ---- PV phase: 9 staged key-steps; wave owns u-slice [wv*128, +128) ----
  f32x4 oacc[2][8];
#pragma unroll
  for (int mt = 0; mt < 2; mt++)
    for (int nt = 0; nt < 8; nt++)
      for (int r = 0; r < 4; r++) oacc[mt][nt][r] = 0.f;

  for (int t = 0; t < 9; t++) {
    int j0 = strip0 + t * 32;
    if (j0 + 31 < 0 || j0 >= S_LEN) continue;  // block-uniform
    // stage VT slab [512 u][32 keys] -> Vl (pitch VP); 8 f16x8 copies per thread
#pragma unroll
    for (int i = 0; i < 8; i++) {
      int u = i * 64 + (tid >> 2);
      int c4 = tid & 3;
      int key = j0 + c4 * 8;
      int kc = key < 0 ? 0 : (key > S_LEN - 8 ? S_LEN - 8 : key);
      f16x8 v = *(const f16x8*)(VT + ((size_t)b * UDIM + u) * S_LEN + kc);
      *(f16x8*)&Vl[u * VP + c4 * 8] = v;
    }
    __syncthreads();
    f16x8 pf0 = *(const f16x8*)&Pb[lm * PP + t * 32 + lq * 8];
    f16x8 pf1 = *(const f16x8*)&Pb[(16 + lm) * PP + t * 32 + lq * 8];
#pragma unroll
    for (int nt = 0; nt < 8; nt++) {
      f16x8 vv = *(const f16x8*)&Vl[(wv * 128 + nt * 16 + lm) * VP + lq * 8];
      oacc[0][nt] = __builtin_amdgcn_mfma_f32_16x16x32_f16(pf0, vv, oacc[0][nt], 0, 0, 0);
      oacc[1][nt] = __builtin_amdgcn_mfma_f32_16x16x32_f16(pf1, vv, oacc[1][nt], 0, 0, 0);
    }
    __syncthreads();
  }

  // ---- epilogue: O /= l, fp32 store ----
  float linv[2][4];
#pragma unroll
  for (int mt = 0; mt < 2; mt++)
    for (int r = 0; r < 4; r++) {
      int row = mt * 16 + lq * 4 + r;
      linv[mt][r] = 1.0f / (wsum[0][row] + wsum[1][row]);
    }
#pragma unroll
  for (int mt = 0; mt < 2; mt++)
    for (int nt = 0; nt < 8; nt++)
      for (int r = 0; r < 4; r++) {
        int row = q0 + mt * 16 + lq * 4 + r;
        int col = wv * 128 + nt * 16 + lm;
        out[(base + row) * (size_t)UDIM + col] = oacc[mt][nt][r] * linv[mt][r];
      }
}

extern "C" void kernel_launch(void* const* d_in, const int* in_sizes, int n_in,
                              void* d_out, int out_size, void* d_ws, size_t ws_size,
                              hipStream_t stream) {
  const float* x  = (const float*)d_in[0];
  const float* Wq = (const float*)d_in[1];
  const float* Wk = (const float*)d_in[2];
  const float* Wv = (const float*)d_in[3];
  const float* bq = (const float*)d_in[4];
  const float* bk = (const float*)d_in[5];
  const float* bv = (const float*)d_in[6];
  float* out = (float*)d_out;

  char* ws = (char*)d_ws;
  const size_t XB_BYTES  = (size_t)BATCH * S_LEN * DDIM * 2;       // 16.8 MB
  const size_t WT_BYTES  = (size_t)3 * DDIM * UDIM * 2;            // 1.5 MB
  const size_t QKV_BYTES = (size_t)3 * BATCH * S_LEN * UDIM * 2;   // 50.3 MB
  f16* xb  = (f16*)ws;
  f16* WT  = (f16*)(ws + XB_BYTES);
  f16* QKV = (f16*)(ws + XB_BYTES + WT_BYTES);
  f16* VT  = (f16*)(ws + XB_BYTES + WT_BYTES + QKV_BYTES);

  int n = BATCH * S_LEN * DDIM;
  cast_f32_f16<<<n / (256 * 4), 256, 0, stream>>>(x, xb, n);
  transpose_w<<<dim3(16, 16, 3), 256, 0, stream>>>(Wq, Wk, Wv, WT);
  gemm_qkv<<<dim3(128, 4, 3), 256, 0, stream>>>(xb, WT, bq, bk, bv, QKV, VT);
  // attn: blockIdx.x = batch so linear id % 8 == batch -> XCD-local K/V in L2
  attn<<<dim3(BATCH, S_LEN / 32), 256, 0, stream>>>(
      QKV, QKV + (size_t)BATCH * S_LEN * UDIM, VT, out);
}